// Round 4
// baseline (691.685 us; speedup 1.0000x reference)
//
#include <hip/hip_runtime.h>

// out[b, f, i, j] = relu(w0[f]*t[b,i] + w1[f]*t[b,j] + w2[f])
// t: (BSZ, SZ) f32, w: (1, NF, 3, 1) f32, out: (BSZ, NF, SZ*SZ) f32
//
// R4 DIAGNOSTIC: write the full output 4x (rotating chunks, idempotent) so the
// kernel dispatch exceeds the ~340 us poison fills and appears in rocprof
// top-5 with its own hbm_gbps/WRITE_SIZE row. This measures our achieved
// store BW directly (fill kernel reference: 6.26 TB/s).

#define BSZ 16
#define SZ  512
#define NF  32

constexpr int ROWS_PER_BLOCK = 64;
constexpr int CHUNKS = SZ / ROWS_PER_BLOCK;   // 8
constexpr int BLOCK  = 256;
constexpr int REPS   = 4;                     // diagnostic multiplier

typedef float vfloat4 __attribute__((ext_vector_type(4)));

__global__ __launch_bounds__(BLOCK) void pairwise_kernel(
    const float* __restrict__ t, const float* __restrict__ w,
    float* __restrict__ out)
{
    __shared__ float tj[SZ];     // w1[f] * t[b, :]
    __shared__ float aif[SZ];    // w0[f] * t[b, :] + w2[f]  (full row, any chunk)

    const int blk   = blockIdx.x;           // b*(NF*CHUNKS) + f*CHUNKS + chunk
    const int chunk = blk & (CHUNKS - 1);
    const int f     = (blk >> 3) & (NF - 1);
    const int b     = blk >> 8;

    const float w0 = w[f * 3 + 0];
    const float w1 = w[f * 3 + 1];
    const float w2 = w[f * 3 + 2];

    const float* tb = t + b * SZ;

    for (int idx = threadIdx.x; idx < SZ; idx += BLOCK) {
        const float tv = tb[idx];
        tj[idx]  = w1 * tv;
        aif[idx] = w0 * tv + w2;
    }
    __syncthreads();

    const int col4 = threadIdx.x & 127;     // column group of 4
    const int rsub = threadIdx.x >> 7;      // 0..1
    const vfloat4 c = ((const vfloat4*)tj)[col4];

    float* fbase = out + (size_t)(b * NF + f) * SZ * SZ;

    for (int rep = 0; rep < REPS; ++rep) {
        const int chunk_r = (chunk + rep) & (CHUNKS - 1);
        const int row0 = chunk_r * ROWS_PER_BLOCK;
        float* outbase = fbase + (size_t)row0 * SZ;
        #pragma unroll
        for (int r = rsub; r < ROWS_PER_BLOCK; r += 2) {
            const float a = aif[row0 + r];
            vfloat4 o;
            o.x = fmaxf(a + c.x, 0.0f);
            o.y = fmaxf(a + c.y, 0.0f);
            o.z = fmaxf(a + c.z, 0.0f);
            o.w = fmaxf(a + c.w, 0.0f);
            ((vfloat4*)(outbase + (size_t)r * SZ))[col4] = o;
        }
    }
}

extern "C" void kernel_launch(void* const* d_in, const int* in_sizes, int n_in,
                              void* d_out, int out_size, void* d_ws, size_t ws_size,
                              hipStream_t stream) {
    const float* t = (const float*)d_in[0];
    const float* w = (const float*)d_in[1];
    float* out = (float*)d_out;

    const int grid = BSZ * NF * CHUNKS;     // 4096 blocks
    pairwise_kernel<<<dim3(grid), dim3(BLOCK), 0, stream>>>(t, w, out);
}